// Round 3
// baseline (533.183 us; speedup 1.0000x reference)
//
#include <hip/hip_runtime.h>

typedef unsigned short u16;
typedef unsigned int   u32;
typedef __attribute__((ext_vector_type(8))) _Float16 half8;
typedef __attribute__((ext_vector_type(4))) _Float16 half4;
typedef __attribute__((ext_vector_type(4))) float    floatx4;

#define GLD16(g, l)                                                            \
  __builtin_amdgcn_global_load_lds(                                            \
      (const __attribute__((address_space(1))) void*)(g),                      \
      (__attribute__((address_space(3))) void*)(l), 16, 0, 0)

// ---------------- f32 -> f16 convert, 8 elems/thread ----------------
__global__ __launch_bounds__(256) void cvt_f16(const float* __restrict__ in,
                                               _Float16* __restrict__ out,
                                               int n8) {
  int i = blockIdx.x * 256 + threadIdx.x;
  if (i >= n8) return;
  const float4* p = (const float4*)in + (size_t)i * 2;
  float4 a = p[0], b = p[1];
  half8 h;
  h[0] = (_Float16)a.x; h[1] = (_Float16)a.y; h[2] = (_Float16)a.z; h[3] = (_Float16)a.w;
  h[4] = (_Float16)b.x; h[5] = (_Float16)b.y; h[6] = (_Float16)b.z; h[7] = (_Float16)b.w;
  *(half8*)(out + (size_t)i * 8) = h;
}

// ---- K/V prep: keys[b,n,v*16+h] -> Kh[(b*16+h)][n][v] f16
//                values            -> Vt[(b*16+h)][v][n] f16 (transposed)
__global__ __launch_bounds__(256) void prep_kv(const float* __restrict__ keys,
                                               const float* __restrict__ values,
                                               _Float16* __restrict__ Kh,
                                               _Float16* __restrict__ Vt) {
  int tid = blockIdx.x * 256 + threadIdx.x;  // < 2M
  {
    int v = tid & 63, n = (tid >> 6) & 511, h = (tid >> 15) & 15, b = tid >> 19;
    Kh[tid] = (_Float16)keys[((size_t)(b * 512 + n)) * 1024 + v * 16 + h];
  }
  {
    int n = tid & 511, v = (tid >> 9) & 63, h = (tid >> 15) & 15, b = tid >> 19;
    Vt[tid] = (_Float16)values[((size_t)(b * 512 + n)) * 1024 + v * 16 + h];
  }
}

// ---------------- GEMM_BT split-K: C[m,n] = sum_k A[m,k]*B[n,k] --------------
// M=2048, N=4096, K=4096 split in 2 (blockIdx.z), 64 iters of BK=32 each.
// 128x128 tile, 4 waves (2x2 of 64x64). LDS slot-swizzled to kill the 8-way
// bank aliasing of the 64B row stride (slot = R*4 + ((chunk + (R>>1)) & 3)).
// MODE 0: z=0 -> Cf[m*4096+n] f32 (no bias); z=1 -> H1[m*4096+n] f16
// MODE 1: scatter both z to f16 q-attn layout (no bias/scale):
//         dst[(((b*16+h)*2048) + s*4+d)*64 + v], z=0 -> H0, z=1 -> H1
template <int MODE>
__global__ __launch_bounds__(256) void gemm_bt(const _Float16* __restrict__ A,
                                               const _Float16* __restrict__ Bw,
                                               float* __restrict__ Cf,
                                               _Float16* __restrict__ H0,
                                               _Float16* __restrict__ H1) {
  const int N = 4096, K = 4096;
  __shared__ _Float16 lA[128 * 32];
  __shared__ _Float16 lB[128 * 32];
  const int t = threadIdx.x;
  const int lane = t & 63;
  const int w = t >> 6;
  const int m0 = blockIdx.y * 128, n0 = blockIdx.x * 128;
  const int kb = blockIdx.z * 2048;
  const int wm = (w >> 1) * 64, wn = (w & 1) * 64;
  const int fr = lane & 15, fq = lane >> 4;

  floatx4 acc[4][4];
#pragma unroll
  for (int i = 0; i < 4; i++)
#pragma unroll
    for (int j = 0; j < 4; j++) acc[i][j] = (floatx4)(0.f);

  // staging with slot swizzle: thread t -> slot t (row t>>2, k-chunk swizzled)
  const int r0 = t >> 2;
  const int kc0 = (((t & 3) - ((t >> 3) & 3)) & 3) * 8;
  const _Float16* gA = A + (size_t)(m0 + r0) * K + kb + kc0;
  const _Float16* gB = Bw + (size_t)(n0 + r0) * K + kb + kc0;
  _Float16* dA = &lA[t * 8];
  _Float16* dB = &lB[t * 8];
  // fragment-read swizzle offset (loop-invariant per lane)
  const int kof = ((fq + ((fr >> 1) & 3)) & 3) * 8;

  for (int k0 = 0; k0 < 2048; k0 += 32) {
    GLD16(gA, dA);
    GLD16(gA + (size_t)64 * K, dA + 2048);
    GLD16(gB, dB);
    GLD16(gB + (size_t)64 * K, dB + 2048);
    gA += 32;
    gB += 32;
    __syncthreads();
    half8 af[4], bf[4];
#pragma unroll
    for (int i = 0; i < 4; i++)
      af[i] = *(const half8*)&lA[(wm + i * 16 + fr) * 32 + kof];
#pragma unroll
    for (int j = 0; j < 4; j++)
      bf[j] = *(const half8*)&lB[(wn + j * 16 + fr) * 32 + kof];
#pragma unroll
    for (int i = 0; i < 4; i++)
#pragma unroll
      for (int j = 0; j < 4; j++)
        acc[i][j] =
            __builtin_amdgcn_mfma_f32_16x16x32_f16(af[i], bf[j], acc[i][j], 0, 0, 0);
    __syncthreads();
  }

  const int z = blockIdx.z;
#pragma unroll
  for (int i = 0; i < 4; i++) {
#pragma unroll
    for (int j = 0; j < 4; j++) {
      const int col = n0 + wn + j * 16 + fr;
      const int rbase = m0 + wm + i * 16 + fq * 4;
      if (MODE == 0) {
        if (z == 0) {
#pragma unroll
          for (int r = 0; r < 4; r++)
            Cf[(size_t)(rbase + r) * N + col] = acc[i][j][r];
        } else {
#pragma unroll
          for (int r = 0; r < 4; r++)
            H1[(size_t)(rbase + r) * N + col] = (_Float16)acc[i][j][r];
        }
      } else {
        _Float16* dst = z ? H1 : H0;
        const int d = col >> 10, v = (col >> 4) & 63, h = col & 15;
#pragma unroll
        for (int r = 0; r < 4; r++) {
          const int row = rbase + r;
          const int b = row >> 9, s = row & 511;
          dst[(((size_t)(b * 16 + h) * 2048) + (s * 4 + d)) * 64 + v] =
              (_Float16)acc[i][j][r];
        }
      }
    }
  }
}

// ---- combine1: qattn = (p0 + p1 + bq[col]) * 0.125, all in q-attn layout ----
__global__ __launch_bounds__(256) void combine1(const _Float16* __restrict__ p0,
                                                const _Float16* __restrict__ p1,
                                                const float* __restrict__ bq,
                                                _Float16* __restrict__ q) {
  const int j8 = (blockIdx.x * 256 + threadIdx.x) * 8;  // 8Mi elems
  half8 a = *(const half8*)(p0 + j8);
  half8 b = *(const half8*)(p1 + j8);
  // j = ((b*16+h)*2048 + s*4+d)*64 + v  ->  col = d*1024 + v*16 + h
  const int v0 = j8 & 63;
  const int d = (j8 >> 6) & 3;
  const int h = (j8 >> 17) & 15;
  const int colbase = d * 1024 + v0 * 16 + h;
  half8 o;
#pragma unroll
  for (int r = 0; r < 8; r++)
    o[r] = (_Float16)(((float)a[r] + (float)b[r] + bq[colbase + r * 16]) * 0.125f);
  *(half8*)(q + j8) = o;
}

// ---- combine2: out[i] += (float)p1[i] + bre[i%4096], in place (race-free) ---
__global__ __launch_bounds__(256) void combine2(float* __restrict__ out,
                                                const _Float16* __restrict__ p1,
                                                const float* __restrict__ bre) {
  const int i4 = (blockIdx.x * 256 + threadIdx.x) * 4;
  float4 o = *(float4*)&out[i4];
  half4 p = *(const half4*)(p1 + i4);
  float4 bb = *(const float4*)&bre[i4 & 4095];
  o.x += (float)p[0] + bb.x;
  o.y += (float)p[1] + bb.y;
  o.z += (float)p[2] + bb.z;
  o.w += (float)p[3] + bb.w;
  *(float4*)&out[i4] = o;
}

// ---------------- MFMA flash attention --------------------------------------
// grid (16 q-tiles, 64 bh), 256 threads = 4 waves. Q-tile 128 rows, 32/wave.
// Q[bh][2048][64] f16 (pre-scaled 1/8), Kh[bh][512][64] f16, Vt[bh][64][512] f16.
// P round-trips through wave-private LDS (C-layout -> A-layout). No barriers.
__global__ __launch_bounds__(256) void attn_mfma(const _Float16* __restrict__ Q,
                                                 const _Float16* __restrict__ Kh,
                                                 const _Float16* __restrict__ Vt,
                                                 float* __restrict__ Out) {
  __shared__ _Float16 Pbuf[4][32][136];
  const int t = threadIdx.x, lane = t & 63, w = t >> 6;
  const int fr = lane & 15, fq = lane >> 4;
  const int bh = blockIdx.y, qt = blockIdx.x;
  const int b = bh >> 4, h = bh & 15;

  const _Float16* Qb = Q + ((size_t)bh * 2048 + qt * 128 + w * 32) * 64;
  const _Float16* Kb = Kh + (size_t)bh * 512 * 64;
  const _Float16* Vb = Vt + (size_t)bh * 64 * 512;

  half8 qf[2][2];
#pragma unroll
  for (int i = 0; i < 2; i++)
#pragma unroll
    for (int ks = 0; ks < 2; ks++)
      qf[i][ks] = *(const half8*)(Qb + (i * 16 + fr) * 64 + ks * 32 + fq * 8);

  floatx4 oacc[2][4];
  float l_acc[2][4];
#pragma unroll
  for (int i = 0; i < 2; i++)
#pragma unroll
    for (int j = 0; j < 4; j++) {
      oacc[i][j] = (floatx4)(0.f);
      l_acc[i][j] = 0.f;
    }

  for (int c0 = 0; c0 < 512; c0 += 128) {
    floatx4 sc[2][8];
#pragma unroll
    for (int i = 0; i < 2; i++)
#pragma unroll
      for (int j = 0; j < 8; j++) sc[i][j] = (floatx4)(0.f);
#pragma unroll
    for (int j = 0; j < 8; j++) {
      const _Float16* kr = Kb + (size_t)(c0 + j * 16 + fr) * 64 + fq * 8;
      half8 k0 = *(const half8*)kr;
      half8 k1 = *(const half8*)(kr + 32);
#pragma unroll
      for (int i = 0; i < 2; i++) {
        sc[i][j] = __builtin_amdgcn_mfma_f32_16x16x32_f16(qf[i][0], k0, sc[i][j], 0, 0, 0);
        sc[i][j] = __builtin_amdgcn_mfma_f32_16x16x32_f16(qf[i][1], k1, sc[i][j], 0, 0, 0);
      }
    }
#pragma unroll
    for (int i = 0; i < 2; i++)
#pragma unroll
      for (int j = 0; j < 8; j++)
#pragma unroll
        for (int r = 0; r < 4; r++) {
          float p = __expf(sc[i][j][r]);
          l_acc[i][r] += p;
          Pbuf[w][i * 16 + fq * 4 + r][j * 16 + fr] = (_Float16)p;
        }
#pragma unroll
    for (int kn = 0; kn < 4; kn++) {
      half8 pa[2];
#pragma unroll
      for (int i = 0; i < 2; i++)
        pa[i] = *(const half8*)&Pbuf[w][i * 16 + fr][kn * 32 + fq * 8];
#pragma unroll
      for (int jv = 0; jv < 4; jv++) {
        half8 vb = *(const half8*)(Vb + (size_t)(jv * 16 + fr) * 512 + c0 + kn * 32 + fq * 8);
#pragma unroll
        for (int i = 0; i < 2; i++)
          oacc[i][jv] = __builtin_amdgcn_mfma_f32_16x16x32_f16(pa[i], vb, oacc[i][jv], 0, 0, 0);
      }
    }
  }

#pragma unroll
  for (int i = 0; i < 2; i++)
#pragma unroll
    for (int r = 0; r < 4; r++) {
#pragma unroll
      for (int m = 8; m; m >>= 1)
        l_acc[i][r] += __shfl_xor(l_acc[i][r], m, 16);
    }
#pragma unroll
  for (int i = 0; i < 2; i++) {
#pragma unroll
    for (int r = 0; r < 4; r++) {
      const float inv = 1.f / l_acc[i][r];
      const int m2 = qt * 128 + w * 32 + i * 16 + fq * 4 + r;
      float* orow = Out + ((size_t)(b * 512 + (m2 >> 2))) * 4096 + h * 256 + (m2 & 3) * 64 + fr;
#pragma unroll
      for (int jv = 0; jv < 4; jv++) orow[jv * 16] = oacc[i][jv][r] * inv;
    }
  }
}

// ---------------- LayerNorm over 4096, output f16 ---------------------------
__global__ __launch_bounds__(256) void ln_kernel(const float* __restrict__ X,
                                                 const float* __restrict__ g,
                                                 const float* __restrict__ bb,
                                                 _Float16* __restrict__ Y) {
  const int row = blockIdx.x;
  const int t = threadIdx.x;
  const float* x = X + (size_t)row * 4096;
  float4 vals[4];
  float sum = 0.f, sq = 0.f;
#pragma unroll
  for (int c = 0; c < 4; c++) {
    vals[c] = *(const float4*)&x[c * 1024 + t * 4];
    sum += vals[c].x + vals[c].y + vals[c].z + vals[c].w;
    sq += vals[c].x * vals[c].x + vals[c].y * vals[c].y + vals[c].z * vals[c].z +
          vals[c].w * vals[c].w;
  }
#pragma unroll
  for (int off = 32; off > 0; off >>= 1) {
    sum += __shfl_down(sum, off, 64);
    sq += __shfl_down(sq, off, 64);
  }
  __shared__ float red[8];
  const int w = t >> 6;
  if ((t & 63) == 0) {
    red[w] = sum;
    red[4 + w] = sq;
  }
  __syncthreads();
  sum = red[0] + red[1] + red[2] + red[3];
  sq = red[4] + red[5] + red[6] + red[7];
  const float mu = sum * (1.f / 4096.f);
  float var = sq * (1.f / 4096.f) - mu * mu;
  var = fmaxf(var, 0.f);
  const float rstd = rsqrtf(var + 1e-12f);
#pragma unroll
  for (int c = 0; c < 4; c++) {
    const int j = c * 1024 + t * 4;
    float4 gg = *(const float4*)&g[j];
    float4 bv = *(const float4*)&bb[j];
    half4 y;
    y[0] = (_Float16)((vals[c].x - mu) * rstd * gg.x + bv.x);
    y[1] = (_Float16)((vals[c].y - mu) * rstd * gg.y + bv.y);
    y[2] = (_Float16)((vals[c].z - mu) * rstd * gg.z + bv.z);
    y[3] = (_Float16)((vals[c].w - mu) * rstd * gg.w + bv.w);
    *(half4*)&Y[(size_t)row * 4096 + j] = y;
  }
}

// ---------------- launcher --------------------------------------------------
extern "C" void kernel_launch(void* const* d_in, const int* in_sizes, int n_in,
                              void* d_out, int out_size, void* d_ws,
                              size_t ws_size, hipStream_t stream) {
  const float* emb = (const float*)d_in[0];
  const float* keys = (const float*)d_in[1];
  const float* values = (const float*)d_in[2];
  const float* Wq = (const float*)d_in[3];
  const float* bq = (const float*)d_in[4];
  const float* Wre = (const float*)d_in[5];
  const float* bre = (const float*)d_in[6];
  const float* ln_g = (const float*)d_in[7];
  const float* ln_b = (const float*)d_in[8];
  float* out = (float*)d_out;

  char* ws = (char*)d_ws;
  // ws timeline (64 MiB), d_out doubles as scratch between stages:
  //  1. embH [0,16) ; WqH [16,48)
  //  2. gemm1 splitK: p0 -> d_out-as-f16, p1 -> [48,64)   (scatter layout)
  //  3. combine1 -> qattn [0,16)          (embH dead)
  //  4. prep_kv -> Kh [48,52), Vt [52,56) (p1 dead)
  //  5. attn -> d_out f32                 (p0 dead)
  //  6. ln -> lnH [16,32)                 (WqH dead)
  //  7. cvt Wre -> [32,64)                (Kh/Vt dead)
  //  8. gemm2 splitK: p0 f32 -> d_out (attnO dead), p1 f16 -> [0,16) (qattn dead)
  //  9. combine2: d_out += p1 + bre       (in place, element-owned)
  _Float16* embH = (_Float16*)(ws);
  _Float16* WqH = (_Float16*)(ws + ((size_t)16 << 20));
  _Float16* p1q = (_Float16*)(ws + ((size_t)48 << 20));
  _Float16* p0q = (_Float16*)d_out;
  _Float16* qattn = (_Float16*)(ws);
  _Float16* Kh = (_Float16*)(ws + ((size_t)48 << 20));
  _Float16* Vt = (_Float16*)(ws + ((size_t)52 << 20));
  _Float16* lnH = (_Float16*)(ws + ((size_t)16 << 20));
  _Float16* WreH = (_Float16*)(ws + ((size_t)32 << 20));
  _Float16* p1o = (_Float16*)(ws);

  cvt_f16<<<4096, 256, 0, stream>>>(emb, embH, 8388608 / 8);
  cvt_f16<<<8192, 256, 0, stream>>>(Wq, WqH, 16777216 / 8);
  gemm_bt<1><<<dim3(32, 16, 2), 256, 0, stream>>>(embH, WqH, nullptr, p0q, p1q);
  combine1<<<4096, 256, 0, stream>>>(p0q, p1q, bq, qattn);
  prep_kv<<<8192, 256, 0, stream>>>(keys, values, Kh, Vt);
  attn_mfma<<<dim3(16, 64), 256, 0, stream>>>(qattn, Kh, Vt, out);
  ln_kernel<<<2048, 256, 0, stream>>>(out, ln_g, ln_b, lnH);
  cvt_f16<<<8192, 256, 0, stream>>>(Wre, WreH, 16777216 / 8);
  gemm_bt<0><<<dim3(32, 16, 2), 256, 0, stream>>>(lnH, WreH, out, nullptr, p1o);
  combine2<<<8192, 256, 0, stream>>>(out, p1o, bre);
}

// Round 5
// 485.674 us; speedup vs baseline: 1.0978x; 1.0978x over previous
//
#include <hip/hip_runtime.h>

typedef __attribute__((ext_vector_type(8))) _Float16 half8;
typedef __attribute__((ext_vector_type(4))) _Float16 half4;
typedef __attribute__((ext_vector_type(4))) float    floatx4;

#define GLD16(g, l)                                                            \
  __builtin_amdgcn_global_load_lds(                                            \
      (const __attribute__((address_space(1))) void*)(g),                      \
      (__attribute__((address_space(3))) void*)(l), 16, 0, 0)

// ---------------- f32 -> f16 convert, 8 elems/thread ----------------
__global__ __launch_bounds__(256) void cvt_f16(const float* __restrict__ in,
                                               _Float16* __restrict__ out,
                                               int n8) {
  int i = blockIdx.x * 256 + threadIdx.x;
  if (i >= n8) return;
  const float4* p = (const float4*)in + (size_t)i * 2;
  float4 a = p[0], b = p[1];
  half8 h;
  h[0] = (_Float16)a.x; h[1] = (_Float16)a.y; h[2] = (_Float16)a.z; h[3] = (_Float16)a.w;
  h[4] = (_Float16)b.x; h[5] = (_Float16)b.y; h[6] = (_Float16)b.z; h[7] = (_Float16)b.w;
  *(half8*)(out + (size_t)i * 8) = h;
}

// ---- K/V prep: keys[b,n,v*16+h] -> Kh[(b*16+h)][n][v] f16
//                values            -> Vt[(b*16+h)][v][n] f16 (transposed)
__global__ __launch_bounds__(256) void prep_kv(const float* __restrict__ keys,
                                               const float* __restrict__ values,
                                               _Float16* __restrict__ Kh,
                                               _Float16* __restrict__ Vt) {
  int tid = blockIdx.x * 256 + threadIdx.x;  // < 2M
  {
    int v = tid & 63, n = (tid >> 6) & 511, h = (tid >> 15) & 15, b = tid >> 19;
    Kh[tid] = (_Float16)keys[((size_t)(b * 512 + n)) * 1024 + v * 16 + h];
  }
  {
    int n = tid & 511, v = (tid >> 9) & 63, h = (tid >> 15) & 15, b = tid >> 19;
    Vt[tid] = (_Float16)values[((size_t)(b * 512 + n)) * 1024 + v * 16 + h];
  }
}

// ---------------- GEMM_BT split-K, BK=64 ------------------------------------
// C[m,n] = sum_k A[m,k]*B[n,k]. M=2048, N=4096, K=4096 split in 2 (blockIdx.z),
// 32 iters of BK=64. 128x128 tile, 4 waves (2x2 of 64x64), 32 KB LDS.
// XOR slot swizzle (chunk c stored at cslot c^(row&7)) kills the bank aliasing
// of the 128B row stride; applied on the global SOURCE address since
// global_load_lds dest must be lane-linear.
// NOTE each partial is 2048*4096*2B = 16 MiB — size buffers accordingly!
// MODE 1 (gemm1): z=0 -> H0 f16 linear, z=1 -> H1 f16 linear
// MODE 0 (gemm2): z=0 -> Cf f32 linear,  z=1 -> H1 f16 linear
template <int MODE>
__global__ __launch_bounds__(256, 3) void gemm_bt(const _Float16* __restrict__ A,
                                                  const _Float16* __restrict__ Bw,
                                                  float* __restrict__ Cf,
                                                  _Float16* __restrict__ H0,
                                                  _Float16* __restrict__ H1) {
  const int K = 4096;
  __shared__ _Float16 lA[128 * 64];
  __shared__ _Float16 lB[128 * 64];
  const int t = threadIdx.x, lane = t & 63, w = t >> 6;
  const int m0 = blockIdx.y * 128, n0 = blockIdx.x * 128;
  const int kb = blockIdx.z * 2048;
  const int wm = (w >> 1) * 64, wn = (w & 1) * 64;
  const int fr = lane & 15, fq = lane >> 4;

  floatx4 acc[4][4];
#pragma unroll
  for (int i = 0; i < 4; i++)
#pragma unroll
    for (int j = 0; j < 4; j++) acc[i][j] = (floatx4)(0.f);

  // slot l = t + 256*j -> row = l>>3 = srow+32j, cslot = t&7;
  // stored chunk = cslot ^ (row&7); (row&7)==(srow&7) since 32j%8==0.
  const int srow = t >> 3;
  const int sch = (t & 7) ^ (srow & 7);
  const _Float16* gA = A + (size_t)(m0 + srow) * K + kb + sch * 8;
  const _Float16* gB = Bw + (size_t)(n0 + srow) * K + kb + sch * 8;
  _Float16* dA = &lA[t * 8];
  _Float16* dB = &lB[t * 8];

  for (int k0 = 0; k0 < 2048; k0 += 64) {
    GLD16(gA, dA);
    GLD16(gA + (size_t)32 * K, dA + 2048);
    GLD16(gA + (size_t)64 * K, dA + 4096);
    GLD16(gA + (size_t)96 * K, dA + 6144);
    GLD16(gB, dB);
    GLD16(gB + (size_t)32 * K, dB + 2048);
    GLD16(gB + (size_t)64 * K, dB + 4096);
    GLD16(gB + (size_t)96 * K, dB + 6144);
    gA += 64;
    gB += 64;
    __syncthreads();
#pragma unroll
    for (int ks = 0; ks < 2; ks++) {
      half8 af[4], bf[4];
#pragma unroll
      for (int i = 0; i < 4; i++) {
        const int rr = wm + i * 16 + fr;
        af[i] = *(const half8*)&lA[rr * 64 + (((ks * 4 + fq) ^ (rr & 7)) * 8)];
      }
#pragma unroll
      for (int j = 0; j < 4; j++) {
        const int rr = wn + j * 16 + fr;
        bf[j] = *(const half8*)&lB[rr * 64 + (((ks * 4 + fq) ^ (rr & 7)) * 8)];
      }
#pragma unroll
      for (int i = 0; i < 4; i++)
#pragma unroll
        for (int j = 0; j < 4; j++)
          acc[i][j] =
              __builtin_amdgcn_mfma_f32_16x16x32_f16(af[i], bf[j], acc[i][j], 0, 0, 0);
    }
    __syncthreads();
  }

  const int z = blockIdx.z;
#pragma unroll
  for (int i = 0; i < 4; i++)
#pragma unroll
    for (int j = 0; j < 4; j++) {
      const int col = n0 + wn + j * 16 + fr;
      const int rbase = m0 + wm + i * 16 + fq * 4;
      if (MODE == 0 && z == 0) {
#pragma unroll
        for (int r = 0; r < 4; r++)
          Cf[(size_t)(rbase + r) * 4096 + col] = acc[i][j][r];
      } else {
        _Float16* P = z ? H1 : H0;
#pragma unroll
        for (int r = 0; r < 4; r++)
          P[(size_t)(rbase + r) * 4096 + col] = (_Float16)acc[i][j][r];
      }
    }
}

// ---- combine1: q = (p0 + p1 + bq) * 0.125, linear [m][col] -> q-attn layout.
// One wave per (m, d): reads 1024 consecutive cols (all 16 h x 64 v for that d)
// coalesced, transposes via wave-private LDS, writes 16B q-segments coalesced.
__global__ __launch_bounds__(256) void combine1(const _Float16* __restrict__ p0,
                                                const _Float16* __restrict__ p1,
                                                const float* __restrict__ bq,
                                                _Float16* __restrict__ q) {
  __shared__ _Float16 T[4][16][80];  // row stride 160B: 16B-aligned, bank-rotating
  const int t = threadIdx.x, L = t & 63, w = t >> 6;
  const int m = blockIdx.x, d = w;
  const int b = m >> 9, s = m & 511;
  const size_t src = (size_t)m * 4096 + d * 1024 + L * 16;
  half8 a0 = *(const half8*)(p0 + src);
  half8 a1 = *(const half8*)(p0 + src + 8);
  half8 b0 = *(const half8*)(p1 + src);
  half8 b1 = *(const half8*)(p1 + src + 8);
  const float4* bqv = (const float4*)(bq + d * 1024 + L * 16);
  float bias[16];
#pragma unroll
  for (int c = 0; c < 4; c++) {
    float4 f = bqv[c];
    bias[c * 4 + 0] = f.x; bias[c * 4 + 1] = f.y;
    bias[c * 4 + 2] = f.z; bias[c * 4 + 3] = f.w;
  }
  // lane L holds v=L, h=0..15: element h -> T[w][h][L]
#pragma unroll
  for (int h = 0; h < 8; h++) {
    T[w][h][L] = (_Float16)(((float)a0[h] + (float)b0[h] + bias[h]) * 0.125f);
    T[w][h + 8][L] =
        (_Float16)(((float)a1[h] + (float)b1[h] + bias[h + 8]) * 0.125f);
  }
  // wave-private LDS round-trip (in-wave DS ordering; same pattern as attn Pbuf)
  const int h2 = L >> 2, c2 = L & 3;
  _Float16* dst = q + (((size_t)(b * 16 + h2) * 2048) + s * 4 + d) * 64 + c2 * 8;
  *(half8*)dst = *(const half8*)&T[w][h2][c2 * 8];
  *(half8*)(dst + 32) = *(const half8*)&T[w][h2][32 + c2 * 8];
}

// ---- combine2: out[i] += (float)p1[i] + bre[i%4096], in place (race-free) ---
__global__ __launch_bounds__(256) void combine2(float* __restrict__ out,
                                                const _Float16* __restrict__ p1,
                                                const float* __restrict__ bre) {
  const int i4 = (blockIdx.x * 256 + threadIdx.x) * 4;
  float4 o = *(float4*)&out[i4];
  half4 p = *(const half4*)(p1 + i4);
  float4 bb = *(const float4*)&bre[i4 & 4095];
  o.x += (float)p[0] + bb.x;
  o.y += (float)p[1] + bb.y;
  o.z += (float)p[2] + bb.z;
  o.w += (float)p[3] + bb.w;
  *(float4*)&out[i4] = o;
}

// ---------------- MFMA flash attention --------------------------------------
// grid (16 q-tiles, 64 bh), 256 threads = 4 waves. Q-tile 128 rows, 32/wave.
// Q[bh][2048][64] f16 (pre-scaled 1/8), Kh[bh][512][64] f16, Vt[bh][64][512] f16.
// P round-trips through wave-private LDS (C-layout -> A-layout). No barriers.
__global__ __launch_bounds__(256) void attn_mfma(const _Float16* __restrict__ Q,
                                                 const _Float16* __restrict__ Kh,
                                                 const _Float16* __restrict__ Vt,
                                                 float* __restrict__ Out) {
  __shared__ _Float16 Pbuf[4][32][136];
  const int t = threadIdx.x, lane = t & 63, w = t >> 6;
  const int fr = lane & 15, fq = lane >> 4;
  const int bh = blockIdx.y, qt = blockIdx.x;
  const int b = bh >> 4, h = bh & 15;

  const _Float16* Qb = Q + ((size_t)bh * 2048 + qt * 128 + w * 32) * 64;
  const _Float16* Kb = Kh + (size_t)bh * 512 * 64;
  const _Float16* Vb = Vt + (size_t)bh * 64 * 512;

  half8 qf[2][2];
#pragma unroll
  for (int i = 0; i < 2; i++)
#pragma unroll
    for (int ks = 0; ks < 2; ks++)
      qf[i][ks] = *(const half8*)(Qb + (i * 16 + fr) * 64 + ks * 32 + fq * 8);

  floatx4 oacc[2][4];
  float l_acc[2][4];
#pragma unroll
  for (int i = 0; i < 2; i++)
#pragma unroll
    for (int j = 0; j < 4; j++) {
      oacc[i][j] = (floatx4)(0.f);
      l_acc[i][j] = 0.f;
    }

  for (int c0 = 0; c0 < 512; c0 += 128) {
    floatx4 sc[2][8];
#pragma unroll
    for (int i = 0; i < 2; i++)
#pragma unroll
      for (int j = 0; j < 8; j++) sc[i][j] = (floatx4)(0.f);
#pragma unroll
    for (int j = 0; j < 8; j++) {
      const _Float16* kr = Kb + (size_t)(c0 + j * 16 + fr) * 64 + fq * 8;
      half8 k0 = *(const half8*)kr;
      half8 k1 = *(const half8*)(kr + 32);
#pragma unroll
      for (int i = 0; i < 2; i++) {
        sc[i][j] = __builtin_amdgcn_mfma_f32_16x16x32_f16(qf[i][0], k0, sc[i][j], 0, 0, 0);
        sc[i][j] = __builtin_amdgcn_mfma_f32_16x16x32_f16(qf[i][1], k1, sc[i][j], 0, 0, 0);
      }
    }
#pragma unroll
    for (int i = 0; i < 2; i++)
#pragma unroll
      for (int j = 0; j < 8; j++)
#pragma unroll
        for (int r = 0; r < 4; r++) {
          float p = __expf(sc[i][j][r]);
          l_acc[i][r] += p;
          Pbuf[w][i * 16 + fq * 4 + r][j * 16 + fr] = (_Float16)p;
        }
#pragma unroll
    for (int kn = 0; kn < 4; kn++) {
      half8 pa[2];
#pragma unroll
      for (int i = 0; i < 2; i++)
        pa[i] = *(const half8*)&Pbuf[w][i * 16 + fr][kn * 32 + fq * 8];
#pragma unroll
      for (int jv = 0; jv < 4; jv++) {
        half8 vb = *(const half8*)(Vb + (size_t)(jv * 16 + fr) * 512 + c0 + kn * 32 + fq * 8);
#pragma unroll
        for (int i = 0; i < 2; i++)
          oacc[i][jv] = __builtin_amdgcn_mfma_f32_16x16x32_f16(pa[i], vb, oacc[i][jv], 0, 0, 0);
      }
    }
  }

#pragma unroll
  for (int i = 0; i < 2; i++)
#pragma unroll
    for (int r = 0; r < 4; r++) {
#pragma unroll
      for (int m = 8; m; m >>= 1)
        l_acc[i][r] += __shfl_xor(l_acc[i][r], m, 16);
    }
#pragma unroll
  for (int i = 0; i < 2; i++) {
#pragma unroll
    for (int r = 0; r < 4; r++) {
      const float inv = 1.f / l_acc[i][r];
      const int m2 = qt * 128 + w * 32 + i * 16 + fq * 4 + r;
      float* orow = Out + ((size_t)(b * 512 + (m2 >> 2))) * 4096 + h * 256 + (m2 & 3) * 64 + fr;
#pragma unroll
      for (int jv = 0; jv < 4; jv++) orow[jv * 16] = oacc[i][jv][r] * inv;
    }
  }
}

// ---------------- LayerNorm over 4096, output f16 ---------------------------
__global__ __launch_bounds__(256) void ln_kernel(const float* __restrict__ X,
                                                 const float* __restrict__ g,
                                                 const float* __restrict__ bb,
                                                 _Float16* __restrict__ Y) {
  const int row = blockIdx.x;
  const int t = threadIdx.x;
  const float* x = X + (size_t)row * 4096;
  float4 vals[4];
  float sum = 0.f, sq = 0.f;
#pragma unroll
  for (int c = 0; c < 4; c++) {
    vals[c] = *(const float4*)&x[c * 1024 + t * 4];
    sum += vals[c].x + vals[c].y + vals[c].z + vals[c].w;
    sq += vals[c].x * vals[c].x + vals[c].y * vals[c].y + vals[c].z * vals[c].z +
          vals[c].w * vals[c].w;
  }
#pragma unroll
  for (int off = 32; off > 0; off >>= 1) {
    sum += __shfl_down(sum, off, 64);
    sq += __shfl_down(sq, off, 64);
  }
  __shared__ float red[8];
  const int w = t >> 6;
  if ((t & 63) == 0) {
    red[w] = sum;
    red[4 + w] = sq;
  }
  __syncthreads();
  sum = red[0] + red[1] + red[2] + red[3];
  sq = red[4] + red[5] + red[6] + red[7];
  const float mu = sum * (1.f / 4096.f);
  float var = sq * (1.f / 4096.f) - mu * mu;
  var = fmaxf(var, 0.f);
  const float rstd = rsqrtf(var + 1e-12f);
#pragma unroll
  for (int c = 0; c < 4; c++) {
    const int j = c * 1024 + t * 4;
    float4 gg = *(const float4*)&g[j];
    float4 bv = *(const float4*)&bb[j];
    half4 y;
    y[0] = (_Float16)((vals[c].x - mu) * rstd * gg.x + bv.x);
    y[1] = (_Float16)((vals[c].y - mu) * rstd * gg.y + bv.y);
    y[2] = (_Float16)((vals[c].z - mu) * rstd * gg.z + bv.z);
    y[3] = (_Float16)((vals[c].w - mu) * rstd * gg.w + bv.w);
    *(half4*)&Y[(size_t)row * 4096 + j] = y;
  }
}

// ---------------- launcher --------------------------------------------------
extern "C" void kernel_launch(void* const* d_in, const int* in_sizes, int n_in,
                              void* d_out, int out_size, void* d_ws,
                              size_t ws_size, hipStream_t stream) {
  const float* emb = (const float*)d_in[0];
  const float* keys = (const float*)d_in[1];
  const float* values = (const float*)d_in[2];
  const float* Wq = (const float*)d_in[3];
  const float* bq = (const float*)d_in[4];
  const float* Wre = (const float*)d_in[5];
  const float* bre = (const float*)d_in[6];
  const float* ln_g = (const float*)d_in[7];
  const float* ln_b = (const float*)d_in[8];
  float* out = (float*)d_out;

  char* ws = (char*)d_ws;
  // ws timeline (64 MiB) + d_out (32 MiB) as scratch. Partials are 16 MiB EACH.
  //  1. embH [0,16) ; WqH [16,48)
  //  2. gemm1<1> splitK: z=0 -> P0q = d_out-as-f16 (16M), z=1 -> P1q [48,64)
  //  3. combine1 -> qattn [0,16)                 (embH dead)
  //  4. prep_kv -> Kh [48,52), Vt [52,56)        (P1q dead)
  //  5. attn -> d_out f32                        (P0q dead)
  //  6. ln -> lnH [16,32)                        (WqH dead)
  //  7. cvt Wre -> WreH [32,64)                  (Kh/Vt dead)
  //  8. gemm2<0> splitK: z=0 -> f32 d_out (attn scratch dead), z=1 -> P1o [0,16)
  //  9. combine2: d_out += p1o + bre             (in place, element-owned)
  _Float16* embH = (_Float16*)(ws);
  _Float16* WqH = (_Float16*)(ws + ((size_t)16 << 20));
  _Float16* P1q = (_Float16*)(ws + ((size_t)48 << 20));
  _Float16* P0q = (_Float16*)d_out;
  _Float16* qattn = (_Float16*)(ws);
  _Float16* Kh = (_Float16*)(ws + ((size_t)48 << 20));
  _Float16* Vt = (_Float16*)(ws + ((size_t)52 << 20));
  _Float16* lnH = (_Float16*)(ws + ((size_t)16 << 20));
  _Float16* WreH = (_Float16*)(ws + ((size_t)32 << 20));
  _Float16* P1o = (_Float16*)(ws);

  cvt_f16<<<4096, 256, 0, stream>>>(emb, embH, 8388608 / 8);
  cvt_f16<<<8192, 256, 0, stream>>>(Wq, WqH, 16777216 / 8);
  gemm_bt<1><<<dim3(32, 16, 2), 256, 0, stream>>>(embH, WqH, nullptr, P0q, P1q);
  combine1<<<2048, 256, 0, stream>>>(P0q, P1q, bq, qattn);
  prep_kv<<<8192, 256, 0, stream>>>(keys, values, Kh, Vt);
  attn_mfma<<<dim3(16, 64), 256, 0, stream>>>(qattn, Kh, Vt, out);
  ln_kernel<<<2048, 256, 0, stream>>>(out, ln_g, ln_b, lnH);
  cvt_f16<<<8192, 256, 0, stream>>>(Wre, WreH, 16777216 / 8);
  gemm_bt<0><<<dim3(32, 16, 2), 256, 0, stream>>>(lnH, WreH, out, nullptr, P1o);
  combine2<<<8192, 256, 0, stream>>>(out, P1o, bre);
}

// Round 6
// 467.013 us; speedup vs baseline: 1.1417x; 1.0400x over previous
//
#include <hip/hip_runtime.h>

typedef __attribute__((ext_vector_type(8))) _Float16 half8;
typedef __attribute__((ext_vector_type(4))) _Float16 half4;
typedef __attribute__((ext_vector_type(4))) float    floatx4;

#define GLD16(g, l)                                                            \
  __builtin_amdgcn_global_load_lds(                                            \
      (const __attribute__((address_space(1))) void*)(g),                      \
      (__attribute__((address_space(3))) void*)(l), 16, 0, 0)

__device__ __forceinline__ void cvt8(const float* __restrict__ in,
                                     _Float16* __restrict__ out, int i) {
  const float4* p = (const float4*)in + (size_t)i * 2;
  float4 a = p[0], b = p[1];
  half8 h;
  h[0] = (_Float16)a.x; h[1] = (_Float16)a.y; h[2] = (_Float16)a.z; h[3] = (_Float16)a.w;
  h[4] = (_Float16)b.x; h[5] = (_Float16)b.y; h[6] = (_Float16)b.z; h[7] = (_Float16)b.w;
  *(half8*)(out + (size_t)i * 8) = h;
}

// ---- prepA (fused): cvt emb (4096 blk) + cvt Wq (8192 blk) + prep_kv (8192) -
__global__ __launch_bounds__(256) void prepA(const float* __restrict__ emb,
                                             const float* __restrict__ Wq,
                                             const float* __restrict__ keys,
                                             const float* __restrict__ values,
                                             _Float16* __restrict__ embH,
                                             _Float16* __restrict__ WqH,
                                             _Float16* __restrict__ Kh,
                                             _Float16* __restrict__ Vt) {
  const int bid = blockIdx.x, t = threadIdx.x;
  if (bid < 4096) {
    cvt8(emb, embH, bid * 256 + t);
  } else if (bid < 12288) {
    cvt8(Wq, WqH, (bid - 4096) * 256 + t);
  } else {
    const int tid = (bid - 12288) * 256 + t;  // < 2M
    {
      int v = tid & 63, n = (tid >> 6) & 511, h = (tid >> 15) & 15, b = tid >> 19;
      Kh[tid] = (_Float16)keys[((size_t)(b * 512 + n)) * 1024 + v * 16 + h];
    }
    {
      int n = tid & 511, v = (tid >> 9) & 63, h = (tid >> 15) & 15, b = tid >> 19;
      Vt[tid] = (_Float16)values[((size_t)(b * 512 + n)) * 1024 + v * 16 + h];
    }
  }
}

// ---------------- GEMM_BT split-K, BK=64 ------------------------------------
// C[m,n] = sum_k A[m,k]*B[n,k]. M=2048, N=4096, K=4096 split in 2 (blockIdx.z),
// 32 iters of BK=64. 128x128 tile, 4 waves (2x2 of 64x64), 32 KB LDS.
// XOR slot swizzle (chunk c stored at cslot c^(row&7)) kills bank aliasing of
// the 128B row stride; applied on the global SOURCE address (global_load_lds
// dest must stay lane-linear). Partials are 2048*4096*2B = 16 MiB EACH.
// MODE 1 (gemm1): z=0 -> H0 f16 linear, z=1 -> H1 f16 linear (no bias)
// MODE 0 (gemm2): z=0 -> Cf f32 linear + bias[col], z=1 -> H1 f16 linear
template <int MODE>
__global__ __launch_bounds__(256, 3) void gemm_bt(const _Float16* __restrict__ A,
                                                  const _Float16* __restrict__ Bw,
                                                  const float* __restrict__ bias,
                                                  float* __restrict__ Cf,
                                                  _Float16* __restrict__ H0,
                                                  _Float16* __restrict__ H1) {
  const int K = 4096;
  __shared__ _Float16 lA[128 * 64];
  __shared__ _Float16 lB[128 * 64];
  const int t = threadIdx.x, lane = t & 63, w = t >> 6;
  const int m0 = blockIdx.y * 128, n0 = blockIdx.x * 128;
  const int kb = blockIdx.z * 2048;
  const int wm = (w >> 1) * 64, wn = (w & 1) * 64;
  const int fr = lane & 15, fq = lane >> 4;

  floatx4 acc[4][4];
#pragma unroll
  for (int i = 0; i < 4; i++)
#pragma unroll
    for (int j = 0; j < 4; j++) acc[i][j] = (floatx4)(0.f);

  const int srow = t >> 3;
  const int sch = (t & 7) ^ (srow & 7);
  const _Float16* gA = A + (size_t)(m0 + srow) * K + kb + sch * 8;
  const _Float16* gB = Bw + (size_t)(n0 + srow) * K + kb + sch * 8;
  _Float16* dA = &lA[t * 8];
  _Float16* dB = &lB[t * 8];

  for (int k0 = 0; k0 < 2048; k0 += 64) {
    GLD16(gA, dA);
    GLD16(gA + (size_t)32 * K, dA + 2048);
    GLD16(gA + (size_t)64 * K, dA + 4096);
    GLD16(gA + (size_t)96 * K, dA + 6144);
    GLD16(gB, dB);
    GLD16(gB + (size_t)32 * K, dB + 2048);
    GLD16(gB + (size_t)64 * K, dB + 4096);
    GLD16(gB + (size_t)96 * K, dB + 6144);
    gA += 64;
    gB += 64;
    __syncthreads();
#pragma unroll
    for (int ks = 0; ks < 2; ks++) {
      half8 af[4], bf[4];
#pragma unroll
      for (int i = 0; i < 4; i++) {
        const int rr = wm + i * 16 + fr;
        af[i] = *(const half8*)&lA[rr * 64 + (((ks * 4 + fq) ^ (rr & 7)) * 8)];
      }
#pragma unroll
      for (int j = 0; j < 4; j++) {
        const int rr = wn + j * 16 + fr;
        bf[j] = *(const half8*)&lB[rr * 64 + (((ks * 4 + fq) ^ (rr & 7)) * 8)];
      }
#pragma unroll
      for (int i = 0; i < 4; i++)
#pragma unroll
        for (int j = 0; j < 4; j++)
          acc[i][j] =
              __builtin_amdgcn_mfma_f32_16x16x32_f16(af[i], bf[j], acc[i][j], 0, 0, 0);
    }
    __syncthreads();
  }

  const int z = blockIdx.z;
#pragma unroll
  for (int i = 0; i < 4; i++)
#pragma unroll
    for (int j = 0; j < 4; j++) {
      const int col = n0 + wn + j * 16 + fr;
      const int rbase = m0 + wm + i * 16 + fq * 4;
      if (MODE == 0 && z == 0) {
        const float bv = bias[col];
#pragma unroll
        for (int r = 0; r < 4; r++)
          Cf[(size_t)(rbase + r) * 4096 + col] = acc[i][j][r] + bv;
      } else {
        _Float16* P = z ? H1 : H0;
#pragma unroll
        for (int r = 0; r < 4; r++)
          P[(size_t)(rbase + r) * 4096 + col] = (_Float16)acc[i][j][r];
      }
    }
}

// ---- prepB (fused): cvt Wre (8192 blk) + combine1 (2048 blk) ----------------
// combine1: q = (p0 + p1 + bq) * 0.125, linear [m][col] -> q-attn layout.
// One wave per (m, d): reads 1024 consecutive cols coalesced, transposes via
// wave-private LDS, writes 16B q-segments coalesced.
__global__ __launch_bounds__(256) void prepB(const float* __restrict__ Wre,
                                             _Float16* __restrict__ WreH,
                                             const _Float16* __restrict__ p0,
                                             const _Float16* __restrict__ p1,
                                             const float* __restrict__ bq,
                                             _Float16* __restrict__ q) {
  const int bid = blockIdx.x, t = threadIdx.x;
  if (bid < 8192) {
    cvt8(Wre, WreH, bid * 256 + t);
    return;
  }
  __shared__ _Float16 T[4][16][80];  // row stride 160B: 16B-aligned, bank-rotating
  const int L = t & 63, w = t >> 6;
  const int m = bid - 8192, d = w;
  const int b = m >> 9, s = m & 511;
  const size_t src = (size_t)m * 4096 + d * 1024 + L * 16;
  half8 a0 = *(const half8*)(p0 + src);
  half8 a1 = *(const half8*)(p0 + src + 8);
  half8 b0 = *(const half8*)(p1 + src);
  half8 b1 = *(const half8*)(p1 + src + 8);
  const float4* bqv = (const float4*)(bq + d * 1024 + L * 16);
  float bias[16];
#pragma unroll
  for (int c = 0; c < 4; c++) {
    float4 f = bqv[c];
    bias[c * 4 + 0] = f.x; bias[c * 4 + 1] = f.y;
    bias[c * 4 + 2] = f.z; bias[c * 4 + 3] = f.w;
  }
#pragma unroll
  for (int h = 0; h < 8; h++) {
    T[w][h][L] = (_Float16)(((float)a0[h] + (float)b0[h] + bias[h]) * 0.125f);
    T[w][h + 8][L] =
        (_Float16)(((float)a1[h] + (float)b1[h] + bias[h + 8]) * 0.125f);
  }
  const int h2 = L >> 2, c2 = L & 3;
  _Float16* dst = q + (((size_t)(b * 16 + h2) * 2048) + s * 4 + d) * 64 + c2 * 8;
  *(half8*)dst = *(const half8*)&T[w][h2][c2 * 8];
  *(half8*)(dst + 32) = *(const half8*)&T[w][h2][32 + c2 * 8];
}

// ---- combine2: out[i] += (float)p1[i], in place (element-owned, race-free) --
__global__ __launch_bounds__(256) void combine2(float* __restrict__ out,
                                                const _Float16* __restrict__ p1) {
  const int i4 = (blockIdx.x * 256 + threadIdx.x) * 4;
  float4 o = *(float4*)&out[i4];
  half4 p = *(const half4*)(p1 + i4);
  o.x += (float)p[0];
  o.y += (float)p[1];
  o.z += (float)p[2];
  o.w += (float)p[3];
  *(float4*)&out[i4] = o;
}

// ---------------- MFMA flash attention --------------------------------------
// grid (16 q-tiles, 64 bh), 256 threads = 4 waves. Q-tile 128 rows, 32/wave.
// Q[bh][2048][64] f16 (pre-scaled 1/8), Kh[bh][512][64] f16, Vt[bh][64][512] f16.
// P round-trips through wave-private LDS (C-layout -> A-layout). No barriers.
__global__ __launch_bounds__(256) void attn_mfma(const _Float16* __restrict__ Q,
                                                 const _Float16* __restrict__ Kh,
                                                 const _Float16* __restrict__ Vt,
                                                 float* __restrict__ Out) {
  __shared__ _Float16 Pbuf[4][32][136];
  const int t = threadIdx.x, lane = t & 63, w = t >> 6;
  const int fr = lane & 15, fq = lane >> 4;
  const int bh = blockIdx.y, qt = blockIdx.x;
  const int b = bh >> 4, h = bh & 15;

  const _Float16* Qb = Q + ((size_t)bh * 2048 + qt * 128 + w * 32) * 64;
  const _Float16* Kb = Kh + (size_t)bh * 512 * 64;
  const _Float16* Vb = Vt + (size_t)bh * 64 * 512;

  half8 qf[2][2];
#pragma unroll
  for (int i = 0; i < 2; i++)
#pragma unroll
    for (int ks = 0; ks < 2; ks++)
      qf[i][ks] = *(const half8*)(Qb + (i * 16 + fr) * 64 + ks * 32 + fq * 8);

  floatx4 oacc[2][4];
  float l_acc[2][4];
#pragma unroll
  for (int i = 0; i < 2; i++)
#pragma unroll
    for (int j = 0; j < 4; j++) {
      oacc[i][j] = (floatx4)(0.f);
      l_acc[i][j] = 0.f;
    }

  for (int c0 = 0; c0 < 512; c0 += 128) {
    floatx4 sc[2][8];
#pragma unroll
    for (int i = 0; i < 2; i++)
#pragma unroll
      for (int j = 0; j < 8; j++) sc[i][j] = (floatx4)(0.f);
#pragma unroll
    for (int j = 0; j < 8; j++) {
      const _Float16* kr = Kb + (size_t)(c0 + j * 16 + fr) * 64 + fq * 8;
      half8 k0 = *(const half8*)kr;
      half8 k1 = *(const half8*)(kr + 32);
#pragma unroll
      for (int i = 0; i < 2; i++) {
        sc[i][j] = __builtin_amdgcn_mfma_f32_16x16x32_f16(qf[i][0], k0, sc[i][j], 0, 0, 0);
        sc[i][j] = __builtin_amdgcn_mfma_f32_16x16x32_f16(qf[i][1], k1, sc[i][j], 0, 0, 0);
      }
    }
#pragma unroll
    for (int i = 0; i < 2; i++)
#pragma unroll
      for (int j = 0; j < 8; j++)
#pragma unroll
        for (int r = 0; r < 4; r++) {
          float p = __expf(sc[i][j][r]);
          l_acc[i][r] += p;
          Pbuf[w][i * 16 + fq * 4 + r][j * 16 + fr] = (_Float16)p;
        }
#pragma unroll
    for (int kn = 0; kn < 4; kn++) {
      half8 pa[2];
#pragma unroll
      for (int i = 0; i < 2; i++)
        pa[i] = *(const half8*)&Pbuf[w][i * 16 + fr][kn * 32 + fq * 8];
#pragma unroll
      for (int jv = 0; jv < 4; jv++) {
        half8 vb = *(const half8*)(Vb + (size_t)(jv * 16 + fr) * 512 + c0 + kn * 32 + fq * 8);
#pragma unroll
        for (int i = 0; i < 2; i++)
          oacc[i][jv] = __builtin_amdgcn_mfma_f32_16x16x32_f16(pa[i], vb, oacc[i][jv], 0, 0, 0);
      }
    }
  }

#pragma unroll
  for (int i = 0; i < 2; i++)
#pragma unroll
    for (int r = 0; r < 4; r++) {
#pragma unroll
      for (int m = 8; m; m >>= 1)
        l_acc[i][r] += __shfl_xor(l_acc[i][r], m, 16);
    }
#pragma unroll
  for (int i = 0; i < 2; i++) {
#pragma unroll
    for (int r = 0; r < 4; r++) {
      const float inv = 1.f / l_acc[i][r];
      const int m2 = qt * 128 + w * 32 + i * 16 + fq * 4 + r;
      float* orow = Out + ((size_t)(b * 512 + (m2 >> 2))) * 4096 + h * 256 + (m2 & 3) * 64 + fr;
#pragma unroll
      for (int jv = 0; jv < 4; jv++) orow[jv * 16] = oacc[i][jv][r] * inv;
    }
  }
}

// ---------------- LayerNorm over 4096, output f16 ---------------------------
__global__ __launch_bounds__(256) void ln_kernel(const float* __restrict__ X,
                                                 const float* __restrict__ g,
                                                 const float* __restrict__ bb,
                                                 _Float16* __restrict__ Y) {
  const int row = blockIdx.x;
  const int t = threadIdx.x;
  const float* x = X + (size_t)row * 4096;
  float4 vals[4];
  float sum = 0.f, sq = 0.f;
#pragma unroll
  for (int c = 0; c < 4; c++) {
    vals[c] = *(const float4*)&x[c * 1024 + t * 4];
    sum += vals[c].x + vals[c].y + vals[c].z + vals[c].w;
    sq += vals[c].x * vals[c].x + vals[c].y * vals[c].y + vals[c].z * vals[c].z +
          vals[c].w * vals[c].w;
  }
#pragma unroll
  for (int off = 32; off > 0; off >>= 1) {
    sum += __shfl_down(sum, off, 64);
    sq += __shfl_down(sq, off, 64);
  }
  __shared__ float red[8];
  const int w = t >> 6;
  if ((t & 63) == 0) {
    red[w] = sum;
    red[4 + w] = sq;
  }
  __syncthreads();
  sum = red[0] + red[1] + red[2] + red[3];
  sq = red[4] + red[5] + red[6] + red[7];
  const float mu = sum * (1.f / 4096.f);
  float var = sq * (1.f / 4096.f) - mu * mu;
  var = fmaxf(var, 0.f);
  const float rstd = rsqrtf(var + 1e-12f);
#pragma unroll
  for (int c = 0; c < 4; c++) {
    const int j = c * 1024 + t * 4;
    float4 gg = *(const float4*)&g[j];
    float4 bv = *(const float4*)&bb[j];
    half4 y;
    y[0] = (_Float16)((vals[c].x - mu) * rstd * gg.x + bv.x);
    y[1] = (_Float16)((vals[c].y - mu) * rstd * gg.y + bv.y);
    y[2] = (_Float16)((vals[c].z - mu) * rstd * gg.z + bv.z);
    y[3] = (_Float16)((vals[c].w - mu) * rstd * gg.w + bv.w);
    *(half4*)&Y[(size_t)row * 4096 + j] = y;
  }
}

// ---------------- launcher --------------------------------------------------
extern "C" void kernel_launch(void* const* d_in, const int* in_sizes, int n_in,
                              void* d_out, int out_size, void* d_ws,
                              size_t ws_size, hipStream_t stream) {
  const float* emb = (const float*)d_in[0];
  const float* keys = (const float*)d_in[1];
  const float* values = (const float*)d_in[2];
  const float* Wq = (const float*)d_in[3];
  const float* bq = (const float*)d_in[4];
  const float* Wre = (const float*)d_in[5];
  const float* bre = (const float*)d_in[6];
  const float* ln_g = (const float*)d_in[7];
  const float* ln_b = (const float*)d_in[8];
  float* out = (float*)d_out;

  char* ws = (char*)d_ws;
  // ws timeline (64 MiB) + d_out (32 MiB) as scratch. GEMM partials 16 MiB EACH.
  //  1. prepA: embH [0,16); WqH [16,48); Kh [48,52); Vt [52,56)
  //  2. gemm1<1>: z=0 -> P0q = d_out[0,16M) f16, z=1 -> P1q = d_out[16M,32M) f16
  //  3. prepB: WreH [16,48) (WqH dead); combine1 -> qattn [0,16) (embH dead)
  //  4. attn(qattn,Kh,Vt) -> d_out f32           (P0q/P1q dead)
  //  5. ln -> lnH [48,64)                        (Kh/Vt dead)
  //  6. gemm2<0>: z=0 -> f32+bre -> d_out (attn scratch dead), z=1 -> P1o [0,16)
  //     (qattn dead)
  //  7. combine2: d_out += P1o                   (in place, element-owned)
  _Float16* embH = (_Float16*)(ws);
  _Float16* WqH = (_Float16*)(ws + ((size_t)16 << 20));
  _Float16* Kh = (_Float16*)(ws + ((size_t)48 << 20));
  _Float16* Vt = (_Float16*)(ws + ((size_t)52 << 20));
  _Float16* P0q = (_Float16*)d_out;
  _Float16* P1q = (_Float16*)((char*)d_out + ((size_t)16 << 20));
  _Float16* WreH = WqH;
  _Float16* qattn = (_Float16*)(ws);
  _Float16* lnH = (_Float16*)(ws + ((size_t)48 << 20));
  _Float16* P1o = (_Float16*)(ws);

  prepA<<<20480, 256, 0, stream>>>(emb, Wq, keys, values, embH, WqH, Kh, Vt);
  gemm_bt<1><<<dim3(32, 16, 2), 256, 0, stream>>>(embH, WqH, nullptr, nullptr,
                                                  P0q, P1q);
  prepB<<<10240, 256, 0, stream>>>(Wre, WreH, P0q, P1q, bq, qattn);
  attn_mfma<<<dim3(16, 64), 256, 0, stream>>>(qattn, Kh, Vt, out);
  ln_kernel<<<2048, 256, 0, stream>>>(out, ln_g, ln_b, lnH);
  gemm_bt<0><<<dim3(32, 16, 2), 256, 0, stream>>>(lnH, WreH, bre, out, nullptr,
                                                  P1o);
  combine2<<<8192, 256, 0, stream>>>(out, P1o);
}